// Round 5
// baseline (15051.328 us; speedup 1.0000x reference)
//
#include <hip/hip_runtime.h>

#define B_   64
#define T_   256
#define H_   512
#define F0_  256
#define C_   32
#define TC   16
#define NCOLS (TC*64)   // 1024

__device__ __forceinline__ float aload(const float* p) {
    return __hip_atomic_load(p, __ATOMIC_RELAXED, __HIP_MEMORY_SCOPE_AGENT);
}
__device__ __forceinline__ void astore(float* p, float v) {
    __hip_atomic_store(p, v, __ATOMIC_RELAXED, __HIP_MEMORY_SCOPE_AGENT);
}

// ---------------- f32 GEMM: pre(4096, NCOLS) = Wih * B^T + bias, 128x128 tile ---
__global__ __launch_bounds__(256) void gemm_f32(
    const float* __restrict__ A, const float* __restrict__ Bsrc,
    const float* __restrict__ bias, float* __restrict__ C,
    int K, int mode, int lo)
{
    __shared__ __align__(16) float As[16][132];
    __shared__ __align__(16) float Bs[16][132];
    const int m0 = blockIdx.y * 128;
    const int n0 = blockIdx.x * 128;
    const int dir = m0 >> 11;
    const int tid = threadIdx.x;
    const int tx = tid & 15, ty = tid >> 4;

    float acc[8][8];
#pragma unroll
    for (int i = 0; i < 8; ++i)
#pragma unroll
        for (int j = 0; j < 8; ++j) acc[i][j] = 0.f;

    for (int k0 = 0; k0 < K; k0 += 16) {
        __syncthreads();
        {
            int row = tid >> 1;
            int cof = (tid & 1) * 8;
            const float* ap = A + (size_t)(m0 + row) * K + k0 + cof;
            float4 v0 = *(const float4*)ap;
            float4 v1 = *(const float4*)(ap + 4);
            As[cof+0][row]=v0.x; As[cof+1][row]=v0.y; As[cof+2][row]=v0.z; As[cof+3][row]=v0.w;
            As[cof+4][row]=v1.x; As[cof+5][row]=v1.y; As[cof+6][row]=v1.z; As[cof+7][row]=v1.w;
        }
        if (mode == 0) {
            int nn = tid >> 1;
            int cof = (tid & 1) * 8;
            int n = n0 + nn;
            int bb = n & 63, tloc = n >> 6;
            int t = dir ? (255 - lo - tloc) : (lo + tloc);
            const float* bp = Bsrc + ((size_t)bb * T_ + t) * F0_ + k0 + cof;
            float4 v0 = *(const float4*)bp;
            float4 v1 = *(const float4*)(bp + 4);
            Bs[cof+0][nn]=v0.x; Bs[cof+1][nn]=v0.y; Bs[cof+2][nn]=v0.z; Bs[cof+3][nn]=v0.w;
            Bs[cof+4][nn]=v1.x; Bs[cof+5][nn]=v1.y; Bs[cof+6][nn]=v1.z; Bs[cof+7][nn]=v1.w;
        } else {
            int kk = tid >> 4;
            int nn = (tid & 15) * 8;
            int n = n0 + nn;
            int tloc = n >> 6, bb = n & 63;
            int t = dir ? (255 - lo - tloc) : (lo + tloc);
            const float* bp = Bsrc + (size_t)t * (1024*64) + (size_t)(k0+kk)*64 + bb;
            float4 v0 = *(const float4*)bp;
            float4 v1 = *(const float4*)(bp + 4);
            *(float4*)&Bs[kk][nn]   = v0;
            *(float4*)&Bs[kk][nn+4] = v1;
        }
        __syncthreads();
#pragma unroll
        for (int kk = 0; kk < 16; ++kk) {
            float4 a0 = *(const float4*)&As[kk][ty*4];
            float4 a1 = *(const float4*)&As[kk][ty*4+64];
            float4 b0 = *(const float4*)&Bs[kk][tx*4];
            float4 b1 = *(const float4*)&Bs[kk][tx*4+64];
            float af[8] = {a0.x,a0.y,a0.z,a0.w,a1.x,a1.y,a1.z,a1.w};
            float bf[8] = {b0.x,b0.y,b0.z,b0.w,b1.x,b1.y,b1.z,b1.w};
#pragma unroll
            for (int i = 0; i < 8; ++i)
#pragma unroll
                for (int j = 0; j < 8; ++j) acc[i][j] += af[i]*bf[j];
        }
    }
#pragma unroll
    for (int i = 0; i < 8; ++i) {
        int ml = (i < 4) ? (ty*4 + i) : (64 + ty*4 + (i-4));
        int m = m0 + ml;
        float bv = bias[m];
        float4 o0, o1;
        o0.x = acc[i][0]+bv; o0.y = acc[i][1]+bv; o0.z = acc[i][2]+bv; o0.w = acc[i][3]+bv;
        o1.x = acc[i][4]+bv; o1.y = acc[i][5]+bv; o1.z = acc[i][6]+bv; o1.w = acc[i][7]+bv;
        *(float4*)&C[(size_t)m*NCOLS + n0 + tx*4]      = o0;
        *(float4*)&C[(size_t)m*NCOLS + n0 + 64 + tx*4] = o1;
    }
}

// ---------------- persistent bidirectional LSTM scan (one t-chunk) -------------
// 256 blocks (dir = bid>>7), 256 threads = 4 k-local x 64 batch, 128KB dyn LDS.
// W: wave-uniform rows -> SCALAR loads (s_load) from global, L2-resident slice.
// h: publish via relaxed agent atomic store (sc1/L3), consume via relaxed
//    agent atomic loads -> no fences anywhere, W stays hot in L2.
// barrier: 8 distributed counters (128B apart), relaxed RMW + relaxed polling.
__global__ __launch_bounds__(256, 1) void lstm_scan(
    const float* __restrict__ Whh,   // (2, 2048, 512)
    const float* __restrict__ pre,   // (4096, NCOLS)
    float* __restrict__ out,         // (T_, 1024, B_)
    float* __restrict__ hbuf,        // [2 parity][2 dir][512][64]
    float* __restrict__ cbuf,        // [2 dir][512][64]
    unsigned* bar,                   // 8 counters, stride 32 dwords
    int lo, int first, unsigned tgt0)
{
    extern __shared__ float smem[];      // 131072 B
    float* hsw = smem;                   // [64][128 float4] swizzled

    const int bid = blockIdx.x;
    const int dir = bid >> 7;
    const int blk = bid & 127;
    const int tid = threadIdx.x;
    const int b   = tid & 63;
    const int kl  = tid >> 6;            // 0..3 (wave-uniform)
    const int k   = blk * 4 + kl;
    const int sk  = __builtin_amdgcn_readfirstlane(k);   // force scalar

    // scalar row pointers (wave-uniform): 4 gate rows of W for this wave's k
    const float* w0p = Whh + ((size_t)(dir*2048 +        sk)) * 512;
    const float* w1p = Whh + ((size_t)(dir*2048 +  512 + sk)) * 512;
    const float* w2p = Whh + ((size_t)(dir*2048 + 1024 + sk)) * 512;
    const float* w3p = Whh + ((size_t)(dir*2048 + 1536 + sk)) * 512;

    float* gb0 = hbuf + (size_t)(0*2 + dir) * (512*64);   // parity 0
    float* gb1 = hbuf + (size_t)(1*2 + dir) * (512*64);   // parity 1
    float* cp  = cbuf + (size_t)dir * (512*64);

    float c;
    if (first) { astore(&gb1[k*64 + b], 0.f); c = 0.f; }  // h_{-1} lives in parity-1
    else       { c = cp[k*64 + b]; }
    asm volatile("s_waitcnt vmcnt(0)" ::: "memory");

    const size_t pr0 = ((size_t)(dir*2048 +        k)) * NCOLS + b;
    const size_t pr1 = ((size_t)(dir*2048 +  512 + k)) * NCOLS + b;
    const size_t pr2 = ((size_t)(dir*2048 + 1024 + k)) * NCOLS + b;
    const size_t pr3 = ((size_t)(dir*2048 + 1536 + k)) * NCOLS + b;

    const float4* hb4 = ((const float4*)hsw) + b*128;
    const int bx = b & 7;
    const int wv = tid >> 6;
    const int mycnt = (bid & 7) * 32;
    unsigned target = tgt0;

    for (int s = 0; s < TC; ++s) {
        const int u = lo + s;
        const int t = dir ? (255 - u) : u;
        const size_t coff = (size_t)s * 64;
        float p0 = pre[pr0 + coff];
        float p1 = pre[pr1 + coff];
        float p2 = pre[pr2 + coff];
        float p3 = pre[pr3 + coff];

        __syncthreads();                               // (A) done with prev step's hsw
        if (tid == 0)
            __hip_atomic_fetch_add(&bar[mycnt], 1u, __ATOMIC_RELAXED, __HIP_MEMORY_SCOPE_AGENT);
        target += 32;
        if (tid < 8) {
            while (__hip_atomic_load(&bar[tid*32], __ATOMIC_RELAXED, __HIP_MEMORY_SCOPE_AGENT) < target)
                __builtin_amdgcn_s_sleep(2);
        }
        __syncthreads();                               // (B) all 256 blocks arrived

        // stage h_{u-1} from parity (u+1)&1 into swizzled LDS (atomic loads, L3)
        const float* src = ((u + 1) & 1) ? gb1 : gb0;
#pragma unroll 4
        for (int i = 0; i < 32; ++i) {
            int g = wv + 4*i;
            float4 v;
            v.x = aload(&src[(4*g+0)*64 + b]);
            v.y = aload(&src[(4*g+1)*64 + b]);
            v.z = aload(&src[(4*g+2)*64 + b]);
            v.w = aload(&src[(4*g+3)*64 + b]);
            ((float4*)hsw)[b*128 + (g ^ bx)] = v;
        }
        __syncthreads();

        float a0 = p0, a1 = p1, a2 = p2, a3 = p3;
#pragma unroll 4
        for (int g = 0; g < 128; ++g) {
            float4 hv = hb4[g ^ bx];                   // LDS (per-lane)
            float4 q0 = *(const float4*)(w0p + 4*g);   // uniform -> s_load
            float4 q1 = *(const float4*)(w1p + 4*g);
            float4 q2 = *(const float4*)(w2p + 4*g);
            float4 q3 = *(const float4*)(w3p + 4*g);
            a0 += q0.x*hv.x + q0.y*hv.y + q0.z*hv.z + q0.w*hv.w;
            a1 += q1.x*hv.x + q1.y*hv.y + q1.z*hv.z + q1.w*hv.w;
            a2 += q2.x*hv.x + q2.y*hv.y + q2.z*hv.z + q2.w*hv.w;
            a3 += q3.x*hv.x + q3.y*hv.y + q3.z*hv.z + q3.w*hv.w;
        }

        float ig = 1.f / (1.f + expf(-a0));
        float fg = 1.f / (1.f + expf(-a1));
        float gg = tanhf(a2);
        float og = 1.f / (1.f + expf(-a3));
        c = fg * c + ig * gg;
        float h = og * tanhf(c);

        out[((size_t)t*1024 + dir*512 + k)*64 + b] = h;
        astore(((u & 1) ? gb1 : gb0) + k*64 + b, h);   // publish to L3
        if (s == TC-1) cp[k*64 + b] = c;
        asm volatile("s_waitcnt vmcnt(0)" ::: "memory");  // h visible before next arrive
    }
}

// ---------------- emissions -----------------------------------------------------
__global__ __launch_bounds__(256) void emis_kernel(
    const float* __restrict__ h1, const float* __restrict__ Wout,
    const float* __restrict__ bout, float* __restrict__ em)
{
    const int s = blockIdx.x;
    const int tid = threadIdx.x;
    const int b = tid & 63;
    const int cl = tid >> 6;
    __shared__ float wl[32][128];
    float acc[8];
#pragma unroll
    for (int u = 0; u < 8; ++u) acc[u] = 0.f;
    const float* hp = h1 + (size_t)s * (1024*64);
    for (int f0 = 0; f0 < 1024; f0 += 128) {
        __syncthreads();
        for (int u = tid; u < 4096; u += 256) {
            int cc = u >> 7, ff = u & 127;
            wl[cc][ff] = Wout[(size_t)cc*1024 + f0 + ff];
        }
        __syncthreads();
        for (int ff = 0; ff < 128; ++ff) {
            float hv = hp[(size_t)(f0+ff)*64 + b];
#pragma unroll
            for (int u = 0; u < 8; ++u) acc[u] += hv * wl[cl + u*4][ff];
        }
    }
#pragma unroll
    for (int u = 0; u < 8; ++u) {
        int cc = cl + u*4;
        em[((size_t)b*T_ + s)*C_ + cc] = acc[u] + bout[cc];
    }
}

// ---------------- CRF Viterbi ---------------------------------------------------
__global__ __launch_bounds__(64) void viterbi_kernel(
    const float* __restrict__ em, const float* __restrict__ start_t,
    const float* __restrict__ end_t, const float* __restrict__ trans,
    float* __restrict__ dout)
{
    const int b = blockIdx.x;
    const int j = threadIdx.x;
    __shared__ float tr[C_*C_];
    __shared__ float sc[2][C_];
    __shared__ unsigned char hist[T_-1][C_];
    for (int i = j; i < C_*C_; i += 64) tr[i] = trans[i];
    const float* emb = em + (size_t)b * T_ * C_;
    if (j < C_) sc[0][j] = start_t[j] + emb[j];
    __syncthreads();
    for (int s = 1; s < T_; ++s) {
        int cur = (s-1) & 1, nxt = s & 1;
        if (j < C_) {
            float best = -3.4e38f; int bi = 0;
            for (int i = 0; i < C_; ++i) {
                float v = sc[cur][i] + tr[i*C_ + j];
                if (v > best) { best = v; bi = i; }
            }
            sc[nxt][j] = best + emb[(size_t)s*C_ + j];
            hist[s-1][j] = (unsigned char)bi;
        }
        __syncthreads();
    }
    if (j == 0) {
        const int cur = (T_-1) & 1;
        float best = -3.4e38f; int bi = 0;
        for (int i = 0; i < C_; ++i) {
            float v = sc[cur][i] + end_t[i];
            if (v > best) { best = v; bi = i; }
        }
        dout[(size_t)B_*T_ + b] = best;
        float* tout = dout + (size_t)b * T_;
        int tag = bi;
        tout[T_-1] = (float)tag;
        for (int s = T_-2; s >= 0; --s) {
            tag = hist[s][tag];
            tout[s] = (float)tag;
        }
    }
}

// ---------------- host launch ---------------------------------------------------
extern "C" void kernel_launch(void* const* d_in, const int* in_sizes, int n_in,
                              void* d_out, int out_size, void* d_ws, size_t ws_size,
                              hipStream_t stream) {
    const float* x    = (const float*)d_in[0];
    const float* Wih0 = (const float*)d_in[2];
    const float* Whh0 = (const float*)d_in[3];
    const float* b0   = (const float*)d_in[4];
    const float* Wih1 = (const float*)d_in[5];
    const float* Whh1 = (const float*)d_in[6];
    const float* b1   = (const float*)d_in[7];
    const float* Wout = (const float*)d_in[8];
    const float* bout = (const float*)d_in[9];
    const float* st   = (const float*)d_in[10];
    const float* en   = (const float*)d_in[11];
    const float* tr   = (const float*)d_in[12];
    float* dout = (float*)d_out;

    char* ws = (char*)d_ws;
    unsigned* bar = (unsigned*)ws;                               // 4 KiB slot (8 counters, 128B apart)
    float* hbuf = (float*)(ws + 4096);                           // 512 KiB
    float* cbuf = (float*)(ws + 4096 + 524288);                  // 256 KiB
    float* em   = (float*)(ws + 4096 + (1u << 20));              // 2 MiB
    float* h0   = (float*)(ws + 4096 + (1u << 20) + (2u << 20)); // 64 MiB
    float* h1   = h0 + (size_t)T_ * 1024 * B_;                   // 64 MiB
    float* pre  = h1 + (size_t)T_ * 1024 * B_;                   // 16.8 MiB

    hipMemsetAsync(bar, 0, 4096, stream);

    const int LDS_BYTES = 131072;
    hipFuncSetAttribute(reinterpret_cast<const void*>(lstm_scan),
                        hipFuncAttributeMaxDynamicSharedMemorySize, LDS_BYTES);

    dim3 bb(256);
    dim3 gg(NCOLS/128, 32);
    for (int ci = 0; ci < 16; ++ci) {
        int lo = ci * TC;
        gemm_f32<<<gg, bb, 0, stream>>>(Wih0, x, b0, pre, F0_, 0, lo);
        lstm_scan<<<256, bb, LDS_BYTES, stream>>>(Whh0, pre, h0, hbuf, cbuf, bar,
                                                  lo, ci == 0 ? 1 : 0, (unsigned)(ci * TC * 32));
    }
    for (int ci = 0; ci < 16; ++ci) {
        int lo = ci * TC;
        gemm_f32<<<gg, bb, 0, stream>>>(Wih1, h0, b1, pre, 1024, 1, lo);
        lstm_scan<<<256, bb, LDS_BYTES, stream>>>(Whh1, pre, h1, hbuf, cbuf, bar,
                                                  lo, ci == 0 ? 1 : 0, (unsigned)((16 + ci) * TC * 32));
    }
    emis_kernel<<<T_, bb, 0, stream>>>(h1, Wout, bout, em);
    viterbi_kernel<<<B_, 64, 0, stream>>>(em, st, en, tr, dout);
}

// Round 6
// 13818.777 us; speedup vs baseline: 1.0892x; 1.0892x over previous
//
#include <hip/hip_runtime.h>

#define B_   64
#define T_   256
#define H_   512
#define F0_  256
#define C_   32
#define TC   16
#define NCOLS (TC*64)   // 1024

__device__ __forceinline__ float aload(const float* p) {
    return __hip_atomic_load(p, __ATOMIC_RELAXED, __HIP_MEMORY_SCOPE_AGENT);
}
__device__ __forceinline__ void astore(float* p, float v) {
    __hip_atomic_store(p, v, __ATOMIC_RELAXED, __HIP_MEMORY_SCOPE_AGENT);
}

// ---------------- f32 GEMM: pre(4096, NCOLS) = Wih * B^T + bias, 128x128 tile ---
__global__ __launch_bounds__(256) void gemm_f32(
    const float* __restrict__ A, const float* __restrict__ Bsrc,
    const float* __restrict__ bias, float* __restrict__ C,
    int K, int mode, int lo)
{
    __shared__ __align__(16) float As[16][132];
    __shared__ __align__(16) float Bs[16][132];
    const int m0 = blockIdx.y * 128;
    const int n0 = blockIdx.x * 128;
    const int dir = m0 >> 11;
    const int tid = threadIdx.x;
    const int tx = tid & 15, ty = tid >> 4;

    float acc[8][8];
#pragma unroll
    for (int i = 0; i < 8; ++i)
#pragma unroll
        for (int j = 0; j < 8; ++j) acc[i][j] = 0.f;

    for (int k0 = 0; k0 < K; k0 += 16) {
        __syncthreads();
        {
            int row = tid >> 1;
            int cof = (tid & 1) * 8;
            const float* ap = A + (size_t)(m0 + row) * K + k0 + cof;
            float4 v0 = *(const float4*)ap;
            float4 v1 = *(const float4*)(ap + 4);
            As[cof+0][row]=v0.x; As[cof+1][row]=v0.y; As[cof+2][row]=v0.z; As[cof+3][row]=v0.w;
            As[cof+4][row]=v1.x; As[cof+5][row]=v1.y; As[cof+6][row]=v1.z; As[cof+7][row]=v1.w;
        }
        if (mode == 0) {
            int nn = tid >> 1;
            int cof = (tid & 1) * 8;
            int n = n0 + nn;
            int bb = n & 63, tloc = n >> 6;
            int t = dir ? (255 - lo - tloc) : (lo + tloc);
            const float* bp = Bsrc + ((size_t)bb * T_ + t) * F0_ + k0 + cof;
            float4 v0 = *(const float4*)bp;
            float4 v1 = *(const float4*)(bp + 4);
            Bs[cof+0][nn]=v0.x; Bs[cof+1][nn]=v0.y; Bs[cof+2][nn]=v0.z; Bs[cof+3][nn]=v0.w;
            Bs[cof+4][nn]=v1.x; Bs[cof+5][nn]=v1.y; Bs[cof+6][nn]=v1.z; Bs[cof+7][nn]=v1.w;
        } else {
            int kk = tid >> 4;
            int nn = (tid & 15) * 8;
            int n = n0 + nn;
            int tloc = n >> 6, bb = n & 63;
            int t = dir ? (255 - lo - tloc) : (lo + tloc);
            const float* bp = Bsrc + (size_t)t * (1024*64) + (size_t)(k0+kk)*64 + bb;
            float4 v0 = *(const float4*)bp;
            float4 v1 = *(const float4*)(bp + 4);
            *(float4*)&Bs[kk][nn]   = v0;
            *(float4*)&Bs[kk][nn+4] = v1;
        }
        __syncthreads();
#pragma unroll
        for (int kk = 0; kk < 16; ++kk) {
            float4 a0 = *(const float4*)&As[kk][ty*4];
            float4 a1 = *(const float4*)&As[kk][ty*4+64];
            float4 b0 = *(const float4*)&Bs[kk][tx*4];
            float4 b1 = *(const float4*)&Bs[kk][tx*4+64];
            float af[8] = {a0.x,a0.y,a0.z,a0.w,a1.x,a1.y,a1.z,a1.w};
            float bf[8] = {b0.x,b0.y,b0.z,b0.w,b1.x,b1.y,b1.z,b1.w};
#pragma unroll
            for (int i = 0; i < 8; ++i)
#pragma unroll
                for (int j = 0; j < 8; ++j) acc[i][j] += af[i]*bf[j];
        }
    }
#pragma unroll
    for (int i = 0; i < 8; ++i) {
        int ml = (i < 4) ? (ty*4 + i) : (64 + ty*4 + (i-4));
        int m = m0 + ml;
        float bv = bias[m];
        float4 o0, o1;
        o0.x = acc[i][0]+bv; o0.y = acc[i][1]+bv; o0.z = acc[i][2]+bv; o0.w = acc[i][3]+bv;
        o1.x = acc[i][4]+bv; o1.y = acc[i][5]+bv; o1.z = acc[i][6]+bv; o1.w = acc[i][7]+bv;
        *(float4*)&C[(size_t)m*NCOLS + n0 + tx*4]      = o0;
        *(float4*)&C[(size_t)m*NCOLS + n0 + 64 + tx*4] = o1;
    }
}

// ---------------- persistent bidirectional LSTM scan (one t-chunk) -------------
// 256 blocks (dir = bid>>7, kg = bid&127 -> 4 k's), 1024 threads = jq(4) x kl(4) x b(64).
// j-reduction split 4-way across jq -> 16 waves/CU = 4 waves/SIMD (latency hiding).
// Partials reduced via LDS (stride-5, conflict-free). Gate g finalized by jq==g
// threads; c/h state owned by jq==0 threads (tid<256).
// W: wave-uniform per-lane global loads (L1 broadcast, vmcnt path).
// h exchange: relaxed agent atomics (L3), no fences. Barrier: 8 distributed ctrs.
__global__ __launch_bounds__(1024, 4) void lstm_scan(
    const float* __restrict__ Whh,   // (2, 2048, 512)
    const float* __restrict__ pre,   // (4096, NCOLS)
    float* __restrict__ out,         // (T_, 1024, B_)
    float* __restrict__ hbuf,        // [2 parity][2 dir][512][64]
    float* __restrict__ cbuf,        // [2 dir][512][64]
    unsigned* bar,                   // 8 counters, stride 32 dwords
    int lo, int first, unsigned tgt0)
{
    extern __shared__ float smem[];          // 161792 B
    float4* hsw4 = (float4*)smem;            // [64][128] swizzled h  (128 KiB)
    float* pacc  = smem + 32768;             // [kl*4+g][5*b+jq] -> 16*320 floats (25 KiB)
    float* actl  = pacc + 5120;              // [kl][5*b+g] -> 4*320 floats (5 KiB)

    const int bid = blockIdx.x;
    const int dir = bid >> 7;
    const int kg  = bid & 127;
    const int tid = threadIdx.x;
    const int b   = tid & 63;
    const int kl  = (tid >> 6) & 3;
    const int jq  = tid >> 8;                // 0..3
    const int k   = kg * 4 + kl;
    const int bx  = b & 7;
    const int gq  = tid >> 6;                // 0..15 stage group

    // W row pointers: 4 gates for this k, j-slice [jq*128, jq*128+128)
    const float* wp0 = Whh + ((size_t)(dir*2048 +        k))*512 + jq*128;
    const float* wp1 = Whh + ((size_t)(dir*2048 +  512 + k))*512 + jq*128;
    const float* wp2 = Whh + ((size_t)(dir*2048 + 1024 + k))*512 + jq*128;
    const float* wp3 = Whh + ((size_t)(dir*2048 + 1536 + k))*512 + jq*128;

    float* gb0 = hbuf + (size_t)(0*2 + dir) * (512*64);   // parity 0
    float* gb1 = hbuf + (size_t)(1*2 + dir) * (512*64);   // parity 1
    float* cp  = cbuf + (size_t)dir * (512*64);

    float c = 0.f;
    if (first) { if (tid < 256) astore(&gb1[k*64 + b], 0.f); }   // h_{-1} in parity-1
    else if (tid < 256) { c = cp[k*64 + b]; }
    asm volatile("s_waitcnt vmcnt(0)" ::: "memory");

    // pre row for this thread's finalize role (gate g = jq)
    const size_t prow = (size_t)(dir*2048 + jq*512 + k) * NCOLS + b;

    const int mycnt = (bid & 7) * 32;
    unsigned target = tgt0;

    for (int s = 0; s < TC; ++s) {
        const int u = lo + s;
        const int t = dir ? (255 - u) : u;
        float p = pre[prow + (size_t)s * 64];

        __syncthreads();                               // (A) done with prev step's LDS
        if (tid == 0)
            __hip_atomic_fetch_add(&bar[mycnt], 1u, __ATOMIC_RELAXED, __HIP_MEMORY_SCOPE_AGENT);
        target += 32;
        if (tid < 8) {
            while (__hip_atomic_load(&bar[tid*32], __ATOMIC_RELAXED, __HIP_MEMORY_SCOPE_AGENT) < target)
                __builtin_amdgcn_s_sleep(2);
        }
        __syncthreads();                               // (B) all 256 blocks arrived

        // stage h_{u-1} (parity (u+1)&1) -> swizzled LDS; 32 atomic dwords/thread
        const float* src = ((u + 1) & 1) ? gb1 : gb0;
#pragma unroll
        for (int i = 0; i < 8; ++i) {
            int g = gq*8 + i;
            float4 v;
            v.x = aload(&src[(4*g+0)*64 + b]);
            v.y = aload(&src[(4*g+1)*64 + b]);
            v.z = aload(&src[(4*g+2)*64 + b]);
            v.w = aload(&src[(4*g+3)*64 + b]);
            hsw4[b*128 + (g ^ bx)] = v;
        }
        __syncthreads();                               // (C) h staged

        // partial dot over this thread's 128 j's, 4 gates
        float a0 = 0.f, a1 = 0.f, a2 = 0.f, a3 = 0.f;
#pragma unroll 4
        for (int i = 0; i < 32; ++i) {
            float4 hv = hsw4[b*128 + ((jq*32 + i) ^ bx)];
            float4 q0 = *(const float4*)(wp0 + 4*i);   // wave-uniform -> L1 broadcast
            float4 q1 = *(const float4*)(wp1 + 4*i);
            float4 q2 = *(const float4*)(wp2 + 4*i);
            float4 q3 = *(const float4*)(wp3 + 4*i);
            a0 += q0.x*hv.x + q0.y*hv.y + q0.z*hv.z + q0.w*hv.w;
            a1 += q1.x*hv.x + q1.y*hv.y + q1.z*hv.z + q1.w*hv.w;
            a2 += q2.x*hv.x + q2.y*hv.y + q2.z*hv.z + q2.w*hv.w;
            a3 += q3.x*hv.x + q3.y*hv.y + q3.z*hv.z + q3.w*hv.w;
        }
        pacc[(kl*4+0)*320 + 5*b + jq] = a0;
        pacc[(kl*4+1)*320 + 5*b + jq] = a1;
        pacc[(kl*4+2)*320 + 5*b + jq] = a2;
        pacc[(kl*4+3)*320 + 5*b + jq] = a3;
        __syncthreads();                               // (D) partials ready

        // finalize gate g = jq for (kl, b)
        {
            const int base = (kl*4 + jq)*320 + 5*b;
            float acc = p + pacc[base+0] + pacc[base+1] + pacc[base+2] + pacc[base+3];
            float av = (jq == 2) ? tanhf(acc) : 1.f / (1.f + expf(-acc));
            actl[kl*320 + 5*b + jq] = av;
        }
        __syncthreads();                               // (E) activations ready

        if (tid < 256) {                               // c/h owners (jq == 0)
            float ig = actl[kl*320 + 5*b + 0];
            float fg = actl[kl*320 + 5*b + 1];
            float gg = actl[kl*320 + 5*b + 2];
            float og = actl[kl*320 + 5*b + 3];
            c = fg * c + ig * gg;
            float h = og * tanhf(c);
            out[((size_t)t*1024 + dir*512 + k)*64 + b] = h;
            astore(((u & 1) ? gb1 : gb0) + k*64 + b, h);   // publish to L3
            if (s == TC-1) cp[k*64 + b] = c;
        }
        asm volatile("s_waitcnt vmcnt(0)" ::: "memory");   // h visible before next arrive
    }
}

// ---------------- emissions -----------------------------------------------------
__global__ __launch_bounds__(256) void emis_kernel(
    const float* __restrict__ h1, const float* __restrict__ Wout,
    const float* __restrict__ bout, float* __restrict__ em)
{
    const int s = blockIdx.x;
    const int tid = threadIdx.x;
    const int b = tid & 63;
    const int cl = tid >> 6;
    __shared__ float wl[32][128];
    float acc[8];
#pragma unroll
    for (int u = 0; u < 8; ++u) acc[u] = 0.f;
    const float* hp = h1 + (size_t)s * (1024*64);
    for (int f0 = 0; f0 < 1024; f0 += 128) {
        __syncthreads();
        for (int u = tid; u < 4096; u += 256) {
            int cc = u >> 7, ff = u & 127;
            wl[cc][ff] = Wout[(size_t)cc*1024 + f0 + ff];
        }
        __syncthreads();
        for (int ff = 0; ff < 128; ++ff) {
            float hv = hp[(size_t)(f0+ff)*64 + b];
#pragma unroll
            for (int u = 0; u < 8; ++u) acc[u] += hv * wl[cl + u*4][ff];
        }
    }
#pragma unroll
    for (int u = 0; u < 8; ++u) {
        int cc = cl + u*4;
        em[((size_t)b*T_ + s)*C_ + cc] = acc[u] + bout[cc];
    }
}

// ---------------- CRF Viterbi ---------------------------------------------------
__global__ __launch_bounds__(64) void viterbi_kernel(
    const float* __restrict__ em, const float* __restrict__ start_t,
    const float* __restrict__ end_t, const float* __restrict__ trans,
    float* __restrict__ dout)
{
    const int b = blockIdx.x;
    const int j = threadIdx.x;
    __shared__ float tr[C_*C_];
    __shared__ float sc[2][C_];
    __shared__ unsigned char hist[T_-1][C_];
    for (int i = j; i < C_*C_; i += 64) tr[i] = trans[i];
    const float* emb = em + (size_t)b * T_ * C_;
    if (j < C_) sc[0][j] = start_t[j] + emb[j];
    __syncthreads();
    for (int s = 1; s < T_; ++s) {
        int cur = (s-1) & 1, nxt = s & 1;
        if (j < C_) {
            float best = -3.4e38f; int bi = 0;
            for (int i = 0; i < C_; ++i) {
                float v = sc[cur][i] + tr[i*C_ + j];
                if (v > best) { best = v; bi = i; }
            }
            sc[nxt][j] = best + emb[(size_t)s*C_ + j];
            hist[s-1][j] = (unsigned char)bi;
        }
        __syncthreads();
    }
    if (j == 0) {
        const int cur = (T_-1) & 1;
        float best = -3.4e38f; int bi = 0;
        for (int i = 0; i < C_; ++i) {
            float v = sc[cur][i] + end_t[i];
            if (v > best) { best = v; bi = i; }
        }
        dout[(size_t)B_*T_ + b] = best;
        float* tout = dout + (size_t)b * T_;
        int tag = bi;
        tout[T_-1] = (float)tag;
        for (int s = T_-2; s >= 0; --s) {
            tag = hist[s][tag];
            tout[s] = (float)tag;
        }
    }
}

// ---------------- host launch ---------------------------------------------------
extern "C" void kernel_launch(void* const* d_in, const int* in_sizes, int n_in,
                              void* d_out, int out_size, void* d_ws, size_t ws_size,
                              hipStream_t stream) {
    const float* x    = (const float*)d_in[0];
    const float* Wih0 = (const float*)d_in[2];
    const float* Whh0 = (const float*)d_in[3];
    const float* b0   = (const float*)d_in[4];
    const float* Wih1 = (const float*)d_in[5];
    const float* Whh1 = (const float*)d_in[6];
    const float* b1   = (const float*)d_in[7];
    const float* Wout = (const float*)d_in[8];
    const float* bout = (const float*)d_in[9];
    const float* st   = (const float*)d_in[10];
    const float* en   = (const float*)d_in[11];
    const float* tr   = (const float*)d_in[12];
    float* dout = (float*)d_out;

    char* ws = (char*)d_ws;
    unsigned* bar = (unsigned*)ws;                               // 4 KiB slot (8 counters, 128B apart)
    float* hbuf = (float*)(ws + 4096);                           // 512 KiB
    float* cbuf = (float*)(ws + 4096 + 524288);                  // 256 KiB
    float* em   = (float*)(ws + 4096 + (1u << 20));              // 2 MiB
    float* h0   = (float*)(ws + 4096 + (1u << 20) + (2u << 20)); // 64 MiB
    float* h1   = h0 + (size_t)T_ * 1024 * B_;                   // 64 MiB
    float* pre  = h1 + (size_t)T_ * 1024 * B_;                   // 16.8 MiB

    hipMemsetAsync(bar, 0, 4096, stream);

    const int LDS_BYTES = 161792;   // 128K hsw + 25K pacc + 5K act (+pad)
    hipFuncSetAttribute(reinterpret_cast<const void*>(lstm_scan),
                        hipFuncAttributeMaxDynamicSharedMemorySize, LDS_BYTES);

    dim3 bb(256);
    dim3 gg(NCOLS/128, 32);
    for (int ci = 0; ci < 16; ++ci) {
        int lo = ci * TC;
        gemm_f32<<<gg, bb, 0, stream>>>(Wih0, x, b0, pre, F0_, 0, lo);
        lstm_scan<<<256, 1024, LDS_BYTES, stream>>>(Whh0, pre, h0, hbuf, cbuf, bar,
                                                    lo, ci == 0 ? 1 : 0, (unsigned)(ci * TC * 32));
    }
    for (int ci = 0; ci < 16; ++ci) {
        int lo = ci * TC;
        gemm_f32<<<gg, bb, 0, stream>>>(Wih1, h0, b1, pre, 1024, 1, lo);
        lstm_scan<<<256, 1024, LDS_BYTES, stream>>>(Whh1, pre, h1, hbuf, cbuf, bar,
                                                    lo, ci == 0 ? 1 : 0, (unsigned)((16 + ci) * TC * 32));
    }
    emis_kernel<<<T_, bb, 0, stream>>>(h1, Wout, bout, em);
    viterbi_kernel<<<B_, 64, 0, stream>>>(em, st, en, tr, dout);
}